// Round 7
// baseline (492.598 us; speedup 1.0000x reference)
//
#include <hip/hip_runtime.h>

#define D 128
#define RPW 16           // rows per wave (f32 GCN gemm)
#define ROWS_PB 64       // rows per block (4 waves * 16)

typedef __attribute__((ext_vector_type(8))) short short8;
typedef __attribute__((ext_vector_type(4))) float f32x4;

static __device__ __forceinline__ ushort f2bf(float f) {
    unsigned u = __float_as_uint(f);
    unsigned r = (u + 0x7fffu + ((u >> 16) & 1u)) >> 16;   // round-to-nearest-even
    return (ushort)r;
}

// ---------------- support = in @ W, 16 rows/wave (f32) -----------------------
__global__ __launch_bounds__(256) void gemm_rowbatch(const float* __restrict__ in,
                                                     const float* __restrict__ W,
                                                     float* __restrict__ out, int N) {
    __shared__ float sh[ROWS_PB][D];
    int tid = threadIdx.x;
    int row0 = blockIdx.x * ROWS_PB;
    for (int i = tid; i < ROWS_PB * (D / 4); i += 256) {
        int r = i >> 5, c4 = i & 31;
        int row = row0 + r;
        float4 v = (row < N) ? ((const float4*)(in + (size_t)row * D))[c4]
                             : make_float4(0.f, 0.f, 0.f, 0.f);
        ((float4*)sh)[i] = v;
    }
    __syncthreads();
    int wid = tid >> 6, lane = tid & 63;
    int rb = wid * RPW;
    float acc0[RPW], acc1[RPW];
#pragma unroll
    for (int r = 0; r < RPW; ++r) { acc0[r] = 0.f; acc1[r] = 0.f; }
    for (int k = 0; k < D; k += 4) {
        float w0[4], w1[4];
#pragma unroll
        for (int kk = 0; kk < 4; ++kk) {
            w0[kk] = W[(k + kk) * D + lane];
            w1[kk] = W[(k + kk) * D + lane + 64];
        }
#pragma unroll
        for (int r = 0; r < RPW; ++r) {
            float4 a4 = *(const float4*)&sh[rb + r][k];
            acc0[r] = fmaf(a4.x, w0[0], acc0[r]); acc1[r] = fmaf(a4.x, w1[0], acc1[r]);
            acc0[r] = fmaf(a4.y, w0[1], acc0[r]); acc1[r] = fmaf(a4.y, w1[1], acc1[r]);
            acc0[r] = fmaf(a4.z, w0[2], acc0[r]); acc1[r] = fmaf(a4.z, w1[2], acc1[r]);
            acc0[r] = fmaf(a4.w, w0[3], acc0[r]); acc1[r] = fmaf(a4.w, w1[3], acc1[r]);
        }
    }
#pragma unroll
    for (int r = 0; r < RPW; ++r) {
        int row = row0 + rb + r;
        if (row < N) {
            out[(size_t)row * D + lane] = acc0[r];
            out[(size_t)row * D + lane + 64] = acc1[r];
        }
    }
}

// ---------------- zero ints --------------------------------------------------
__global__ void zero_int4(int4* __restrict__ p, int n4) {
    int i = blockIdx.x * blockDim.x + threadIdx.x;
    if (i < n4) p[i] = make_int4(0, 0, 0, 0);
}

// ---------------- combined histogram over dst for both layers ----------------
__global__ void hist2_kernel(const int* __restrict__ dst, int* __restrict__ counts,
                             int E2, int E, int N) {
    int i = blockIdx.x * blockDim.x + threadIdx.x;
    if (i >= E2) return;
    int off = (i >= E) ? N : 0;
    atomicAdd(&counts[off + dst[i]], 1);
}

// ---------------- multi-block scan: pass 1 (block partial sums) --------------
__global__ __launch_bounds__(256) void scan_partial(const int4* __restrict__ counts4,
                                                    int* __restrict__ bsum) {
    int b = blockIdx.x, t = threadIdx.x;
    int4 c0 = counts4[(size_t)b * 512 + t * 2];
    int4 c1 = counts4[(size_t)b * 512 + t * 2 + 1];
    int s = c0.x + c0.y + c0.z + c0.w + c1.x + c1.y + c1.z + c1.w;
#pragma unroll
    for (int d = 1; d < 64; d <<= 1) s += __shfl_xor(s, d);
    __shared__ int ws[4];
    if ((t & 63) == 0) ws[t >> 6] = s;
    __syncthreads();
    if (t == 0) bsum[b] = ws[0] + ws[1] + ws[2] + ws[3];
}

// ---------------- multi-block scan: pass 2 (scan of block sums, 1 wave) ------
__global__ void scan_base(const int* __restrict__ bsum, int* __restrict__ bbase, int nb) {
    int lane = threadIdx.x;   // launched with 64 threads
    int run = 0;
    for (int c = 0; c < nb; c += 64) {
        int v = (c + lane < nb) ? bsum[c + lane] : 0;
        int inc = v;
#pragma unroll
        for (int d = 1; d < 64; d <<= 1) {
            int y = __shfl_up(inc, d);
            if (lane >= d) inc += y;
        }
        if (c + lane < nb) bbase[c + lane] = run + inc - v;
        run += __shfl(inc, 63);
    }
}

// ---------------- multi-block scan: pass 3 (apply) ---------------------------
__global__ __launch_bounds__(256) void scan_apply(const int4* __restrict__ counts4,
                                                  const int* __restrict__ bbase,
                                                  int4* __restrict__ off4,
                                                  int4* __restrict__ cur4) {
    __shared__ int ts[256];
    int b = blockIdx.x, t = threadIdx.x;
    int4 c0 = counts4[(size_t)b * 512 + t * 2];
    int4 c1 = counts4[(size_t)b * 512 + t * 2 + 1];
    int s = c0.x + c0.y + c0.z + c0.w + c1.x + c1.y + c1.z + c1.w;
    ts[t] = s;
    __syncthreads();
    for (int d = 1; d < 256; d <<= 1) {
        int x = ts[t];
        int y = (t >= d) ? ts[t - d] : 0;
        __syncthreads();
        ts[t] = x + y;
        __syncthreads();
    }
    int base = bbase[b] + ((t == 0) ? 0 : ts[t - 1]);
    int4 o0, o1;
    o0.x = base;
    o0.y = o0.x + c0.x;
    o0.z = o0.y + c0.y;
    o0.w = o0.z + c0.z;
    o1.x = o0.w + c0.w;
    o1.y = o1.x + c1.x;
    o1.z = o1.y + c1.y;
    o1.w = o1.z + c1.z;
    off4[(size_t)b * 512 + t * 2] = o0;
    off4[(size_t)b * 512 + t * 2 + 1] = o1;
    cur4[(size_t)b * 512 + t * 2] = o0;
    cur4[(size_t)b * 512 + t * 2 + 1] = o1;
}

// ---------------- CSR build: scatter (src,w) into dst-sorted slots -----------
__global__ void fill_kernel(const int* __restrict__ src, const int* __restrict__ dst,
                            const float* __restrict__ w, int* __restrict__ cursor,
                            int sub, int2* __restrict__ srcw, int E) {
    int e = blockIdx.x * blockDim.x + threadIdx.x;
    if (e >= E) return;
    int p = atomicAdd(&cursor[dst[e]], 1) - sub;
    srcw[p] = make_int2(src[e], __float_as_int(w[e]));
}

// ---------------- gather: agg[n] = relu(sum_e w*sup[src] + bias) -------------
// One wave per node; lane l owns channels 2l, 2l+1 (float2). 4-edge pipeline.
__global__ void gather_nodes(const float* __restrict__ sup, const int2* __restrict__ srcw,
                             const int* __restrict__ offsets, int sub,
                             const float* __restrict__ bias,
                             float* __restrict__ out, int N) {
    int node = (blockIdx.x * blockDim.x + threadIdx.x) >> 6;
    int lane = threadIdx.x & 63;
    if (node >= N) return;
    int lo = offsets[node] - sub, hi = offsets[node + 1] - sub;
    float ax = 0.f, ay = 0.f;
    int c = lane * 2;
    int j = lo;
    for (; j + 4 <= hi; j += 4) {
        int2 s0 = srcw[j], s1 = srcw[j + 1], s2 = srcw[j + 2], s3 = srcw[j + 3];
        float2 v0 = *(const float2*)(sup + (size_t)s0.x * D + c);
        float2 v1 = *(const float2*)(sup + (size_t)s1.x * D + c);
        float2 v2 = *(const float2*)(sup + (size_t)s2.x * D + c);
        float2 v3 = *(const float2*)(sup + (size_t)s3.x * D + c);
        float w0 = __int_as_float(s0.y), w1 = __int_as_float(s1.y);
        float w2 = __int_as_float(s2.y), w3 = __int_as_float(s3.y);
        ax = fmaf(w0, v0.x, ax); ay = fmaf(w0, v0.y, ay);
        ax = fmaf(w1, v1.x, ax); ay = fmaf(w1, v1.y, ay);
        ax = fmaf(w2, v2.x, ax); ay = fmaf(w2, v2.y, ay);
        ax = fmaf(w3, v3.x, ax); ay = fmaf(w3, v3.y, ay);
    }
    for (; j < hi; ++j) {
        int2 sw = srcw[j];
        float wt = __int_as_float(sw.y);
        float2 v = *(const float2*)(sup + (size_t)sw.x * D + c);
        ax = fmaf(wt, v.x, ax); ay = fmaf(wt, v.y, ay);
    }
    float2 bi = *(const float2*)(bias + c);
    float2 o;
    o.x = fmaxf(ax + bi.x, 0.f);
    o.y = fmaxf(ay + bi.y, 0.f);
    *(float2*)(out + (size_t)node * D + c) = o;
}

// ---------------- weight transpose + bf16 convert ----------------------------
__global__ void convW(const float* __restrict__ Wx, const float* __restrict__ Wh,
                      ushort* __restrict__ wxt, ushort* __restrict__ wht) {
    int i = blockIdx.x * blockDim.x + threadIdx.x;
    if (i >= 384 * 128) return;
    int c = i >> 7, k = i & 127;
    wxt[i] = f2bf(Wx[(size_t)k * 384 + c]);
    wht[i] = f2bf(Wh[(size_t)k * 384 + c]);
}

// ---------------- fused GRU via bf16 MFMA ------------------------------------
// Wave = one (16-row stripe, m-tile) pair: 8x more waves than the m-loop
// version -> latency hidden by TLP. ~40 global loads + 24 MFMA per wave.
__global__ __launch_bounds__(256) void gru_mfma(const float* __restrict__ h,
                                                const float* __restrict__ hidden,
                                                const ushort* __restrict__ wxt,
                                                const ushort* __restrict__ wht,
                                                const float* __restrict__ bx,
                                                const float* __restrict__ bh,
                                                float* __restrict__ out, int N) {
    int wid = threadIdx.x >> 6, lane = threadIdx.x & 63;
    int gw = blockIdx.x * 4 + wid;
    int nstripes = (N + 15) >> 4;
    int stripe = gw >> 3;
    int m = gw & 7;
    if (stripe >= nstripes) return;
    int row0 = stripe * 16;
    int lr = lane & 15;
    int lk = (lane >> 4) * 8;

    // A-fragments: convert f32 -> bf16 in-register.
    int arow = row0 + lr; if (arow >= N) arow = N - 1;   // tail-safe (dup row, rows unused)
    short8 Ah[4], Ad[4];
    const float* hrow = h + (size_t)arow * D + lk;
    const float* drow = hidden + (size_t)arow * D + lk;
#pragma unroll
    for (int ks = 0; ks < 4; ++ks) {
        float4 a0 = *(const float4*)(hrow + ks * 32);
        float4 a1 = *(const float4*)(hrow + ks * 32 + 4);
        float4 c0 = *(const float4*)(drow + ks * 32);
        float4 c1 = *(const float4*)(drow + ks * 32 + 4);
        short8 va, vc;
        va[0] = f2bf(a0.x); va[1] = f2bf(a0.y); va[2] = f2bf(a0.z); va[3] = f2bf(a0.w);
        va[4] = f2bf(a1.x); va[5] = f2bf(a1.y); va[6] = f2bf(a1.z); va[7] = f2bf(a1.w);
        vc[0] = f2bf(c0.x); vc[1] = f2bf(c0.y); vc[2] = f2bf(c0.z); vc[3] = f2bf(c0.w);
        vc[4] = f2bf(c1.x); vc[5] = f2bf(c1.y); vc[6] = f2bf(c1.z); vc[7] = f2bf(c1.w);
        Ah[ks] = va;
        Ad[ks] = vc;
    }
    int orow = row0 + (lane >> 4) * 4;

    int col = m * 16 + lr;
    const ushort* bxp = wxt + (size_t)col * D + lk;
    const ushort* bhp = wht + (size_t)col * D + lk;
    f32x4 ax0{}, ax1{}, ax2{}, ah0{}, ah1{}, ah2{};
#pragma unroll
    for (int ks = 0; ks < 4; ++ks) {
        short8 w0 = *(const short8*)(bxp + ks * 32);
        short8 w1 = *(const short8*)(bxp + 128 * D + ks * 32);
        short8 w2 = *(const short8*)(bxp + 256 * D + ks * 32);
        short8 v0 = *(const short8*)(bhp + ks * 32);
        short8 v1 = *(const short8*)(bhp + 128 * D + ks * 32);
        short8 v2 = *(const short8*)(bhp + 256 * D + ks * 32);
        ax0 = __builtin_amdgcn_mfma_f32_16x16x32_bf16(Ah[ks], w0, ax0, 0, 0, 0);
        ax1 = __builtin_amdgcn_mfma_f32_16x16x32_bf16(Ah[ks], w1, ax1, 0, 0, 0);
        ax2 = __builtin_amdgcn_mfma_f32_16x16x32_bf16(Ah[ks], w2, ax2, 0, 0, 0);
        ah0 = __builtin_amdgcn_mfma_f32_16x16x32_bf16(Ad[ks], v0, ah0, 0, 0, 0);
        ah1 = __builtin_amdgcn_mfma_f32_16x16x32_bf16(Ad[ks], v1, ah1, 0, 0, 0);
        ah2 = __builtin_amdgcn_mfma_f32_16x16x32_bf16(Ad[ks], v2, ah2, 0, 0, 0);
    }

    float bxr = bx[col], bxi = bx[col + 128], bxn = bx[col + 256];
    float bhr = bh[col], bhi = bh[col + 128], bhn = bh[col + 256];
#pragma unroll
    for (int r = 0; r < 4; ++r) {
        int row = orow + r;
        if (row < N) {
            float ir = ax0[r] + bxr, hr = ah0[r] + bhr;
            float ii = ax1[r] + bxi, hi = ah1[r] + bhi;
            float in_ = ax2[r] + bxn, hn = ah2[r] + bhn;
            float rg = 1.f / (1.f + __expf(-(ir + hr)));
            float ig = 1.f / (1.f + __expf(-(ii + hi)));
            float nx = in_ + rg * hn;
            float ng = 1.f - 2.f / (__expf(2.f * nx) + 1.f);   // tanh(nx)
            float hv = hidden[(size_t)row * D + col];
            out[(size_t)row * D + col] = ng + ig * (hv - ng);
        }
    }
}

extern "C" void kernel_launch(void* const* d_in, const int* in_sizes, int n_in,
                              void* d_out, int out_size, void* d_ws, size_t ws_size,
                              hipStream_t stream) {
    const float* x      = (const float*)d_in[0];
    const float* hidden = (const float*)d_in[1];
    const int*   adj_src = (const int*)d_in[2];
    const int*   adj_dst = (const int*)d_in[3];
    const float* adj_w   = (const float*)d_in[4];
    const float* gcn_W   = (const float*)d_in[5];
    const float* gcn_b   = (const float*)d_in[6];
    const float* x2h_W   = (const float*)d_in[7];
    const float* x2h_b   = (const float*)d_in[8];
    const float* h2h_W   = (const float*)d_in[9];
    const float* h2h_b   = (const float*)d_in[10];
    float* out = (float*)d_out;

    const int L = 2;
    const int N = in_sizes[0] / D;        // 50000
    const int E = in_sizes[2] / L;        // 800000
    const size_t nd = (size_t)N * D;

    const int twoN   = 2 * N;
    const int NB     = (twoN + 2047) / 2048;      // scan blocks (49)
    const int padded = NB * 2048;

    char* ws = (char*)d_ws;
    float* A        = (float*)ws;                 ws += nd * 4;             // support
    float* B        = (float*)ws;                 ws += nd * 4;             // agg / h
    int*   counts2  = (int*)ws;                   ws += (size_t)padded * 4;
    int*   offsets2 = (int*)ws;                   ws += ((size_t)padded + 64) * 4;
    int*   cursor2  = (int*)ws;                   ws += ((size_t)padded + 64) * 4;
    int*   bsum     = (int*)ws;                   ws += ((size_t)NB + 64) * 4;
    int*   bbase    = (int*)ws;                   ws += ((size_t)NB + 64) * 4;
    int2*  srcw     = (int2*)ws;                  ws += (size_t)E * 8;
    ushort* wxt     = (ushort*)ws;                ws += (size_t)384 * 128 * 2;
    ushort* wht     = (ushort*)ws;                ws += (size_t)384 * 128 * 2;

    dim3 blk(256);
    int batch_blocks = (N + ROWS_PB - 1) / ROWS_PB;
    int gat_blocks   = (N + 3) / 4;
    int edge_blocks  = (E + 255) / 256;
    int e2_blocks    = (2 * E + 255) / 256;
    int zero_blocks  = (padded / 4 + 255) / 256;
    int convw_blocks = (384 * 128 + 255) / 256;
    int nstripes     = (N + 15) / 16;
    int gru_blocks   = (nstripes * 8 + 3) / 4;    // one wave per (stripe, m-tile)

    convW<<<convw_blocks, blk, 0, stream>>>(x2h_W, h2h_W, wxt, wht);

    // combined CSR metadata for both layers (counts/offsets/cursor over 2N)
    zero_int4<<<zero_blocks, blk, 0, stream>>>((int4*)counts2, padded / 4);
    hist2_kernel<<<e2_blocks, blk, 0, stream>>>(adj_dst, counts2, 2 * E, E, N);
    scan_partial<<<NB, blk, 0, stream>>>((const int4*)counts2, bsum);
    scan_base<<<1, 64, 0, stream>>>(bsum, bbase, NB);
    scan_apply<<<NB, blk, 0, stream>>>((const int4*)counts2, bbase,
                                       (int4*)offsets2, (int4*)cursor2);

    const float* hcur = x;
    for (int l = 0; l < L; ++l) {
        gemm_rowbatch<<<batch_blocks, blk, 0, stream>>>(hcur, gcn_W + (size_t)l * D * D, A, N);
        fill_kernel<<<edge_blocks, blk, 0, stream>>>(adj_src + (size_t)l * E,
                                                     adj_dst + (size_t)l * E,
                                                     adj_w + (size_t)l * E,
                                                     cursor2 + (size_t)l * N, l * E,
                                                     srcw, E);
        gather_nodes<<<gat_blocks, blk, 0, stream>>>(A, srcw, offsets2 + (size_t)l * N, l * E,
                                                     gcn_b + (size_t)l * D, B, N);
        hcur = B;
    }
    gru_mfma<<<gru_blocks, blk, 0, stream>>>(B, hidden, wxt, wht, x2h_b, h2h_b, out, N);
}

// Round 8
// 454.040 us; speedup vs baseline: 1.0849x; 1.0849x over previous
//
#include <hip/hip_runtime.h>

#define D 128
#define RPW 8            // rows per wave (f32 GCN gemm)
#define ROWS_PB 32       // rows per block (4 waves * 8)

typedef __attribute__((ext_vector_type(8))) short short8;
typedef __attribute__((ext_vector_type(4))) float f32x4;

static __device__ __forceinline__ ushort f2bf(float f) {
    unsigned u = __float_as_uint(f);
    unsigned r = (u + 0x7fffu + ((u >> 16) & 1u)) >> 16;   // round-to-nearest-even
    return (ushort)r;
}

// ---------------- support = in @ W, W staged in LDS --------------------------
// LDS: W 64KB + 32 input rows 16KB = 80KB -> 2 blocks/CU. W-col reads are
// 2-way bank aliases (free); input-row reads are same-address broadcasts.
__global__ __launch_bounds__(256) void gemm_rowbatch(const float* __restrict__ in,
                                                     const float* __restrict__ W,
                                                     float* __restrict__ out, int N) {
    __shared__ float sw[D * D];          // 64 KB
    __shared__ float sh[ROWS_PB][D];     // 16 KB
    int tid = threadIdx.x;
    int row0 = blockIdx.x * ROWS_PB;
    for (int j = tid; j < D * D / 4; j += 256)
        ((float4*)sw)[j] = ((const float4*)W)[j];
    for (int i = tid; i < ROWS_PB * (D / 4); i += 256) {
        int r = i >> 5, c4 = i & 31;
        int row = row0 + r;
        float4 v = (row < N) ? ((const float4*)(in + (size_t)row * D))[c4]
                             : make_float4(0.f, 0.f, 0.f, 0.f);
        ((float4*)sh)[i] = v;
    }
    __syncthreads();
    int wid = tid >> 6, lane = tid & 63;
    int rb = wid * RPW;
    float acc0[RPW], acc1[RPW];
#pragma unroll
    for (int r = 0; r < RPW; ++r) { acc0[r] = 0.f; acc1[r] = 0.f; }
    for (int k = 0; k < D; k += 4) {
        float w0[4], w1[4];
#pragma unroll
        for (int kk = 0; kk < 4; ++kk) {
            w0[kk] = sw[(k + kk) * D + lane];
            w1[kk] = sw[(k + kk) * D + lane + 64];
        }
#pragma unroll
        for (int r = 0; r < RPW; ++r) {
            float4 a4 = *(const float4*)&sh[rb + r][k];
            acc0[r] = fmaf(a4.x, w0[0], acc0[r]); acc1[r] = fmaf(a4.x, w1[0], acc1[r]);
            acc0[r] = fmaf(a4.y, w0[1], acc0[r]); acc1[r] = fmaf(a4.y, w1[1], acc1[r]);
            acc0[r] = fmaf(a4.z, w0[2], acc0[r]); acc1[r] = fmaf(a4.z, w1[2], acc1[r]);
            acc0[r] = fmaf(a4.w, w0[3], acc0[r]); acc1[r] = fmaf(a4.w, w1[3], acc1[r]);
        }
    }
#pragma unroll
    for (int r = 0; r < RPW; ++r) {
        int row = row0 + rb + r;
        if (row < N) {
            out[(size_t)row * D + lane] = acc0[r];
            out[(size_t)row * D + lane + 64] = acc1[r];
        }
    }
}

// ---------------- zero ints --------------------------------------------------
__global__ void zero_int4(int4* __restrict__ p, int n4) {
    int i = blockIdx.x * blockDim.x + threadIdx.x;
    if (i < n4) p[i] = make_int4(0, 0, 0, 0);
}

// ---------------- combined histogram over dst for both layers ----------------
__global__ void hist2_kernel(const int* __restrict__ dst, int* __restrict__ counts,
                             int E2, int E, int N) {
    int i = blockIdx.x * blockDim.x + threadIdx.x;
    if (i >= E2) return;
    int off = (i >= E) ? N : 0;
    atomicAdd(&counts[off + dst[i]], 1);
}

// ---------------- multi-block scan: pass 1 (block partial sums) --------------
__global__ __launch_bounds__(256) void scan_partial(const int4* __restrict__ counts4,
                                                    int* __restrict__ bsum) {
    int b = blockIdx.x, t = threadIdx.x;
    int4 c0 = counts4[(size_t)b * 512 + t * 2];
    int4 c1 = counts4[(size_t)b * 512 + t * 2 + 1];
    int s = c0.x + c0.y + c0.z + c0.w + c1.x + c1.y + c1.z + c1.w;
#pragma unroll
    for (int d = 1; d < 64; d <<= 1) s += __shfl_xor(s, d);
    __shared__ int ws[4];
    if ((t & 63) == 0) ws[t >> 6] = s;
    __syncthreads();
    if (t == 0) bsum[b] = ws[0] + ws[1] + ws[2] + ws[3];
}

// ---------------- multi-block scan: pass 2 (scan of block sums, 1 wave) ------
__global__ void scan_base(const int* __restrict__ bsum, int* __restrict__ bbase, int nb) {
    int lane = threadIdx.x;   // launched with 64 threads
    int run = 0;
    for (int c = 0; c < nb; c += 64) {
        int v = (c + lane < nb) ? bsum[c + lane] : 0;
        int inc = v;
#pragma unroll
        for (int d = 1; d < 64; d <<= 1) {
            int y = __shfl_up(inc, d);
            if (lane >= d) inc += y;
        }
        if (c + lane < nb) bbase[c + lane] = run + inc - v;
        run += __shfl(inc, 63);
    }
}

// ---------------- multi-block scan: pass 3 (apply) ---------------------------
__global__ __launch_bounds__(256) void scan_apply(const int4* __restrict__ counts4,
                                                  const int* __restrict__ bbase,
                                                  int4* __restrict__ off4,
                                                  int4* __restrict__ cur4) {
    __shared__ int ts[256];
    int b = blockIdx.x, t = threadIdx.x;
    int4 c0 = counts4[(size_t)b * 512 + t * 2];
    int4 c1 = counts4[(size_t)b * 512 + t * 2 + 1];
    int s = c0.x + c0.y + c0.z + c0.w + c1.x + c1.y + c1.z + c1.w;
    ts[t] = s;
    __syncthreads();
    for (int d = 1; d < 256; d <<= 1) {
        int x = ts[t];
        int y = (t >= d) ? ts[t - d] : 0;
        __syncthreads();
        ts[t] = x + y;
        __syncthreads();
    }
    int base = bbase[b] + ((t == 0) ? 0 : ts[t - 1]);
    int4 o0, o1;
    o0.x = base;
    o0.y = o0.x + c0.x;
    o0.z = o0.y + c0.y;
    o0.w = o0.z + c0.z;
    o1.x = o0.w + c0.w;
    o1.y = o1.x + c1.x;
    o1.z = o1.y + c1.y;
    o1.w = o1.z + c1.z;
    off4[(size_t)b * 512 + t * 2] = o0;
    off4[(size_t)b * 512 + t * 2 + 1] = o1;
    cur4[(size_t)b * 512 + t * 2] = o0;
    cur4[(size_t)b * 512 + t * 2 + 1] = o1;
}

// ---------------- CSR build: scatter (src,w) into dst-sorted slots -----------
__global__ void fill_kernel(const int* __restrict__ src, const int* __restrict__ dst,
                            const float* __restrict__ w, int* __restrict__ cursor,
                            int sub, int2* __restrict__ srcw, int E) {
    int e = blockIdx.x * blockDim.x + threadIdx.x;
    if (e >= E) return;
    int p = atomicAdd(&cursor[dst[e]], 1) - sub;
    srcw[p] = make_int2(src[e], __float_as_int(w[e]));
}

// ---------------- gather: agg[n] = relu(sum_e w*sup[src] + bias) -------------
__global__ void gather_nodes(const float* __restrict__ sup, const int2* __restrict__ srcw,
                             const int* __restrict__ offsets, int sub,
                             const float* __restrict__ bias,
                             float* __restrict__ out, int N) {
    int node = (blockIdx.x * blockDim.x + threadIdx.x) >> 6;
    int lane = threadIdx.x & 63;
    if (node >= N) return;
    int lo = offsets[node] - sub, hi = offsets[node + 1] - sub;
    float ax = 0.f, ay = 0.f;
    int c = lane * 2;
    int j = lo;
    for (; j + 4 <= hi; j += 4) {
        int2 s0 = srcw[j], s1 = srcw[j + 1], s2 = srcw[j + 2], s3 = srcw[j + 3];
        float2 v0 = *(const float2*)(sup + (size_t)s0.x * D + c);
        float2 v1 = *(const float2*)(sup + (size_t)s1.x * D + c);
        float2 v2 = *(const float2*)(sup + (size_t)s2.x * D + c);
        float2 v3 = *(const float2*)(sup + (size_t)s3.x * D + c);
        float w0 = __int_as_float(s0.y), w1 = __int_as_float(s1.y);
        float w2 = __int_as_float(s2.y), w3 = __int_as_float(s3.y);
        ax = fmaf(w0, v0.x, ax); ay = fmaf(w0, v0.y, ay);
        ax = fmaf(w1, v1.x, ax); ay = fmaf(w1, v1.y, ay);
        ax = fmaf(w2, v2.x, ax); ay = fmaf(w2, v2.y, ay);
        ax = fmaf(w3, v3.x, ax); ay = fmaf(w3, v3.y, ay);
    }
    for (; j < hi; ++j) {
        int2 sw = srcw[j];
        float wt = __int_as_float(sw.y);
        float2 v = *(const float2*)(sup + (size_t)sw.x * D + c);
        ax = fmaf(wt, v.x, ax); ay = fmaf(wt, v.y, ay);
    }
    float2 bi = *(const float2*)(bias + c);
    float2 o;
    o.x = fmaxf(ax + bi.x, 0.f);
    o.y = fmaxf(ay + bi.y, 0.f);
    *(float2*)(out + (size_t)node * D + c) = o;
}

// ---------------- weight transpose + bf16 convert ----------------------------
__global__ void convW(const float* __restrict__ Wx, const float* __restrict__ Wh,
                      ushort* __restrict__ wxt, ushort* __restrict__ wht) {
    int i = blockIdx.x * blockDim.x + threadIdx.x;
    if (i >= 384 * 128) return;
    int c = i >> 7, k = i & 127;
    wxt[i] = f2bf(Wx[(size_t)k * 384 + c]);
    wht[i] = f2bf(Wh[(size_t)k * 384 + c]);
}

// ---------------- fused GRU via bf16 MFMA, weights staged in LDS -------------
// Block = 4 waves = 4 stripes. Weights processed in 4 quarters (2 m-tiles
// each); each quarter = 2 mats x 3 gates x 32 cols x 128 k bf16 staged into
// 51 KB LDS (k padded to 136 -> conflict-free ds_read_b128). 3 blocks/CU.
// A-fragments converted to bf16 once, held in registers across quarters.
#define QROWS 192                 // 2 mats * 3 gates * 32 cols
#define KPAD 136
__global__ __launch_bounds__(256) void gru_mfma_lds(const float* __restrict__ h,
                                                    const float* __restrict__ hidden,
                                                    const ushort* __restrict__ wxt,
                                                    const ushort* __restrict__ wht,
                                                    const float* __restrict__ bx,
                                                    const float* __restrict__ bh,
                                                    float* __restrict__ out, int N) {
    __shared__ ushort lw[QROWS * KPAD];          // 51 KB
    int tid = threadIdx.x;
    int wid = tid >> 6, lane = tid & 63;
    int nstripes = (N + 15) >> 4;
    int stripe = blockIdx.x * 4 + wid;
    bool live = stripe < nstripes;
    int row0 = stripe * 16;
    int lr = lane & 15;
    int lk = (lane >> 4) * 8;

    // A-fragments (held across all quarters)
    short8 Ah[4], Ad[4];
    if (live) {
        const float* hrow = h + (size_t)(row0 + lr) * D + lk;
        const float* drow = hidden + (size_t)(row0 + lr) * D + lk;
#pragma unroll
        for (int ks = 0; ks < 4; ++ks) {
            float4 a0 = *(const float4*)(hrow + ks * 32);
            float4 a1 = *(const float4*)(hrow + ks * 32 + 4);
            float4 c0 = *(const float4*)(drow + ks * 32);
            float4 c1 = *(const float4*)(drow + ks * 32 + 4);
            short8 va, vc;
            va[0] = f2bf(a0.x); va[1] = f2bf(a0.y); va[2] = f2bf(a0.z); va[3] = f2bf(a0.w);
            va[4] = f2bf(a1.x); va[5] = f2bf(a1.y); va[6] = f2bf(a1.z); va[7] = f2bf(a1.w);
            vc[0] = f2bf(c0.x); vc[1] = f2bf(c0.y); vc[2] = f2bf(c0.z); vc[3] = f2bf(c0.w);
            vc[4] = f2bf(c1.x); vc[5] = f2bf(c1.y); vc[6] = f2bf(c1.z); vc[7] = f2bf(c1.w);
            Ah[ks] = va;
            Ad[ks] = vc;
        }
    }
    int orow = row0 + (lane >> 4) * 4;

    for (int q = 0; q < 4; ++q) {
        if (q) __syncthreads();            // compute of previous quarter done
        // stage quarter q: rows g*128 + q*32 + c of wxt/wht
        for (int j = tid; j < QROWS * 16; j += 256) {
            int chunk = j & 15;            // 8-ushort chunk within k
            int row = j >> 4;              // 0..191
            int mat = row >= 96;
            int r = row - (mat ? 96 : 0);
            int g = r >> 5;
            int c = r & 31;
            const ushort* src = (mat ? wht : wxt)
                              + ((size_t)(g * 128 + q * 32 + c) << 7) + (chunk << 3);
            *(short8*)&lw[row * KPAD + chunk * 8] = *(const short8*)src;
        }
        __syncthreads();
        if (!live) continue;

#pragma unroll
        for (int mt = 0; mt < 2; ++mt) {
            int cl = mt * 16 + lr;                     // col within quarter (0..31)
            const ushort* bx0 = lw + (0 * 32 + cl) * KPAD + lk;     // mat x, gate r
            const ushort* bx1 = lw + (1 * 32 + cl) * KPAD + lk;     // gate i
            const ushort* bx2 = lw + (2 * 32 + cl) * KPAD + lk;     // gate n
            const ushort* bh0 = lw + ((96 + 0 * 32) + cl) * KPAD + lk;
            const ushort* bh1 = lw + ((96 + 1 * 32) + cl) * KPAD + lk;
            const ushort* bh2 = lw + ((96 + 2 * 32) + cl) * KPAD + lk;
            f32x4 ax0{}, ax1{}, ax2{}, ah0{}, ah1{}, ah2{};
#pragma unroll
            for (int ks = 0; ks < 4; ++ks) {
                short8 w0 = *(const short8*)(bx0 + ks * 32);
                short8 w1 = *(const short8*)(bx1 + ks * 32);
                short8 w2 = *(const short8*)(bx2 + ks * 32);
                short8 v0 = *(const short8*)(bh0 + ks * 32);
                short8 v1 = *(const short8*)(bh1 + ks * 32);
                short8 v2 = *(const short8*)(bh2 + ks * 32);
                ax0 = __builtin_amdgcn_mfma_f32_16x16x32_bf16(Ah[ks], w0, ax0, 0, 0, 0);
                ax1 = __builtin_amdgcn_mfma_f32_16x16x32_bf16(Ah[ks], w1, ax1, 0, 0, 0);
                ax2 = __builtin_amdgcn_mfma_f32_16x16x32_bf16(Ah[ks], w2, ax2, 0, 0, 0);
                ah0 = __builtin_amdgcn_mfma_f32_16x16x32_bf16(Ad[ks], v0, ah0, 0, 0, 0);
                ah1 = __builtin_amdgcn_mfma_f32_16x16x32_bf16(Ad[ks], v1, ah1, 0, 0, 0);
                ah2 = __builtin_amdgcn_mfma_f32_16x16x32_bf16(Ad[ks], v2, ah2, 0, 0, 0);
            }
            int col = q * 32 + mt * 16 + lr;           // 0..127
            float bxr = bx[col], bxi = bx[col + 128], bxn = bx[col + 256];
            float bhr = bh[col], bhi = bh[col + 128], bhn = bh[col + 256];
#pragma unroll
            for (int r = 0; r < 4; ++r) {
                int row = orow + r;
                if (row < N) {
                    float ir = ax0[r] + bxr, hr = ah0[r] + bhr;
                    float ii = ax1[r] + bxi, hi = ah1[r] + bhi;
                    float in_ = ax2[r] + bxn, hn = ah2[r] + bhn;
                    float rg = 1.f / (1.f + __expf(-(ir + hr)));
                    float ig = 1.f / (1.f + __expf(-(ii + hi)));
                    float nx = in_ + rg * hn;
                    float ng = 1.f - 2.f / (__expf(2.f * nx) + 1.f);   // tanh(nx)
                    float hv = hidden[(size_t)row * D + col];
                    out[(size_t)row * D + col] = ng + ig * (hv - ng);
                }
            }
        }
    }
}

extern "C" void kernel_launch(void* const* d_in, const int* in_sizes, int n_in,
                              void* d_out, int out_size, void* d_ws, size_t ws_size,
                              hipStream_t stream) {
    const float* x      = (const float*)d_in[0];
    const float* hidden = (const float*)d_in[1];
    const int*   adj_src = (const int*)d_in[2];
    const int*   adj_dst = (const int*)d_in[3];
    const float* adj_w   = (const float*)d_in[4];
    const float* gcn_W   = (const float*)d_in[5];
    const float* gcn_b   = (const float*)d_in[6];
    const float* x2h_W   = (const float*)d_in[7];
    const float* x2h_b   = (const float*)d_in[8];
    const float* h2h_W   = (const float*)d_in[9];
    const float* h2h_b   = (const float*)d_in[10];
    float* out = (float*)d_out;

    const int L = 2;
    const int N = in_sizes[0] / D;        // 50000
    const int E = in_sizes[2] / L;        // 800000
    const size_t nd = (size_t)N * D;

    const int twoN   = 2 * N;
    const int NB     = (twoN + 2047) / 2048;      // scan blocks (49)
    const int padded = NB * 2048;

    char* ws = (char*)d_ws;
    float* A        = (float*)ws;                 ws += nd * 4;             // support
    float* B        = (float*)ws;                 ws += nd * 4;             // agg / h
    int*   counts2  = (int*)ws;                   ws += (size_t)padded * 4;
    int*   offsets2 = (int*)ws;                   ws += ((size_t)padded + 64) * 4;
    int*   cursor2  = (int*)ws;                   ws += ((size_t)padded + 64) * 4;
    int*   bsum     = (int*)ws;                   ws += ((size_t)NB + 64) * 4;
    int*   bbase    = (int*)ws;                   ws += ((size_t)NB + 64) * 4;
    int2*  srcw     = (int2*)ws;                  ws += (size_t)E * 8;
    ushort* wxt     = (ushort*)ws;                ws += (size_t)384 * 128 * 2;
    ushort* wht     = (ushort*)ws;                ws += (size_t)384 * 128 * 2;

    dim3 blk(256);
    int batch_blocks = (N + ROWS_PB - 1) / ROWS_PB;
    int gat_blocks   = (N + 3) / 4;
    int edge_blocks  = (E + 255) / 256;
    int e2_blocks    = (2 * E + 255) / 256;
    int zero_blocks  = (padded / 4 + 255) / 256;
    int convw_blocks = (384 * 128 + 255) / 256;
    int nstripes     = (N + 15) / 16;
    int gru_blocks   = (nstripes + 3) / 4;

    convW<<<convw_blocks, blk, 0, stream>>>(x2h_W, h2h_W, wxt, wht);

    // combined CSR metadata for both layers (counts/offsets/cursor over 2N)
    zero_int4<<<zero_blocks, blk, 0, stream>>>((int4*)counts2, padded / 4);
    hist2_kernel<<<e2_blocks, blk, 0, stream>>>(adj_dst, counts2, 2 * E, E, N);
    scan_partial<<<NB, blk, 0, stream>>>((const int4*)counts2, bsum);
    scan_base<<<1, 64, 0, stream>>>(bsum, bbase, NB);
    scan_apply<<<NB, blk, 0, stream>>>((const int4*)counts2, bbase,
                                       (int4*)offsets2, (int4*)cursor2);

    const float* hcur = x;
    for (int l = 0; l < L; ++l) {
        gemm_rowbatch<<<batch_blocks, blk, 0, stream>>>(hcur, gcn_W + (size_t)l * D * D, A, N);
        fill_kernel<<<edge_blocks, blk, 0, stream>>>(adj_src + (size_t)l * E,
                                                     adj_dst + (size_t)l * E,
                                                     adj_w + (size_t)l * E,
                                                     cursor2 + (size_t)l * N, l * E,
                                                     srcw, E);
        gather_nodes<<<gat_blocks, blk, 0, stream>>>(A, srcw, offsets2 + (size_t)l * N, l * E,
                                                     gcn_b + (size_t)l * D, B, N);
        hcur = B;
    }
    gru_mfma_lds<<<gru_blocks, blk, 0, stream>>>(B, hidden, wxt, wht, x2h_b, h2h_b, out, N);
}

// Round 9
// 379.819 us; speedup vs baseline: 1.2969x; 1.1954x over previous
//
#include <hip/hip_runtime.h>

#define D 128
#define RPW 8            // rows per wave (f32 GCN gemm)
#define ROWS_PB 32       // rows per block (4 waves * 8)

typedef __attribute__((ext_vector_type(8))) short short8;
typedef __attribute__((ext_vector_type(4))) float f32x4;

static __device__ __forceinline__ ushort f2bf(float f) {
    unsigned u = __float_as_uint(f);
    unsigned r = (u + 0x7fffu + ((u >> 16) & 1u)) >> 16;   // round-to-nearest-even
    return (ushort)r;
}

// ---------------- support = in @ W, W staged in LDS --------------------------
__global__ __launch_bounds__(256) void gemm_rowbatch(const float* __restrict__ in,
                                                     const float* __restrict__ W,
                                                     float* __restrict__ out, int N) {
    __shared__ float sw[D * D];          // 64 KB
    __shared__ float sh[ROWS_PB][D];     // 16 KB
    int tid = threadIdx.x;
    int row0 = blockIdx.x * ROWS_PB;
    for (int j = tid; j < D * D / 4; j += 256)
        ((float4*)sw)[j] = ((const float4*)W)[j];
    for (int i = tid; i < ROWS_PB * (D / 4); i += 256) {
        int r = i >> 5, c4 = i & 31;
        int row = row0 + r;
        float4 v = (row < N) ? ((const float4*)(in + (size_t)row * D))[c4]
                             : make_float4(0.f, 0.f, 0.f, 0.f);
        ((float4*)sh)[i] = v;
    }
    __syncthreads();
    int wid = tid >> 6, lane = tid & 63;
    int rb = wid * RPW;
    float acc0[RPW], acc1[RPW];
#pragma unroll
    for (int r = 0; r < RPW; ++r) { acc0[r] = 0.f; acc1[r] = 0.f; }
    for (int k = 0; k < D; k += 4) {
        float w0[4], w1[4];
#pragma unroll
        for (int kk = 0; kk < 4; ++kk) {
            w0[kk] = sw[(k + kk) * D + lane];
            w1[kk] = sw[(k + kk) * D + lane + 64];
        }
#pragma unroll
        for (int r = 0; r < RPW; ++r) {
            float4 a4 = *(const float4*)&sh[rb + r][k];
            acc0[r] = fmaf(a4.x, w0[0], acc0[r]); acc1[r] = fmaf(a4.x, w1[0], acc1[r]);
            acc0[r] = fmaf(a4.y, w0[1], acc0[r]); acc1[r] = fmaf(a4.y, w1[1], acc1[r]);
            acc0[r] = fmaf(a4.z, w0[2], acc0[r]); acc1[r] = fmaf(a4.z, w1[2], acc1[r]);
            acc0[r] = fmaf(a4.w, w0[3], acc0[r]); acc1[r] = fmaf(a4.w, w1[3], acc1[r]);
        }
    }
#pragma unroll
    for (int r = 0; r < RPW; ++r) {
        int row = row0 + rb + r;
        if (row < N) {
            out[(size_t)row * D + lane] = acc0[r];
            out[(size_t)row * D + lane + 64] = acc1[r];
        }
    }
}

// ---------------- zero ints --------------------------------------------------
__global__ void zero_int4(int4* __restrict__ p, int n4) {
    int i = blockIdx.x * blockDim.x + threadIdx.x;
    if (i < n4) p[i] = make_int4(0, 0, 0, 0);
}

// ---------------- slot: histogram + keep local slot (1 atomic/edge total) ----
__global__ void slot_kernel(const int* __restrict__ dst, int* __restrict__ counts,
                            ushort* __restrict__ pl, int E2, int E, int N) {
    int i = blockIdx.x * blockDim.x + threadIdx.x;
    if (i >= E2) return;
    int off = (i >= E) ? N : 0;
    pl[i] = (ushort)atomicAdd(&counts[off + dst[i]], 1);
}

// ---------------- multi-block scan: pass 1 (block partial sums) --------------
__global__ __launch_bounds__(256) void scan_partial(const int4* __restrict__ counts4,
                                                    int* __restrict__ bsum) {
    int b = blockIdx.x, t = threadIdx.x;
    int4 c0 = counts4[(size_t)b * 512 + t * 2];
    int4 c1 = counts4[(size_t)b * 512 + t * 2 + 1];
    int s = c0.x + c0.y + c0.z + c0.w + c1.x + c1.y + c1.z + c1.w;
#pragma unroll
    for (int d = 1; d < 64; d <<= 1) s += __shfl_xor(s, d);
    __shared__ int ws[4];
    if ((t & 63) == 0) ws[t >> 6] = s;
    __syncthreads();
    if (t == 0) bsum[b] = ws[0] + ws[1] + ws[2] + ws[3];
}

// ---------------- multi-block scan: pass 2 (scan of block sums, 1 wave) ------
__global__ void scan_base(const int* __restrict__ bsum, int* __restrict__ bbase, int nb) {
    int lane = threadIdx.x;   // launched with 64 threads
    int run = 0;
    for (int c = 0; c < nb; c += 64) {
        int v = (c + lane < nb) ? bsum[c + lane] : 0;
        int inc = v;
#pragma unroll
        for (int d = 1; d < 64; d <<= 1) {
            int y = __shfl_up(inc, d);
            if (lane >= d) inc += y;
        }
        if (c + lane < nb) bbase[c + lane] = run + inc - v;
        run += __shfl(inc, 63);
    }
}

// ---------------- multi-block scan: pass 3 (apply) ---------------------------
__global__ __launch_bounds__(256) void scan_apply(const int4* __restrict__ counts4,
                                                  const int* __restrict__ bbase,
                                                  int4* __restrict__ off4) {
    __shared__ int ts[256];
    int b = blockIdx.x, t = threadIdx.x;
    int4 c0 = counts4[(size_t)b * 512 + t * 2];
    int4 c1 = counts4[(size_t)b * 512 + t * 2 + 1];
    int s = c0.x + c0.y + c0.z + c0.w + c1.x + c1.y + c1.z + c1.w;
    ts[t] = s;
    __syncthreads();
    for (int d = 1; d < 256; d <<= 1) {
        int x = ts[t];
        int y = (t >= d) ? ts[t - d] : 0;
        __syncthreads();
        ts[t] = x + y;
        __syncthreads();
    }
    int base = bbase[b] + ((t == 0) ? 0 : ts[t - 1]);
    int4 o0, o1;
    o0.x = base;
    o0.y = o0.x + c0.x;
    o0.z = o0.y + c0.y;
    o0.w = o0.z + c0.z;
    o1.x = o0.w + c0.w;
    o1.y = o1.x + c1.x;
    o1.z = o1.y + c1.y;
    o1.w = o1.z + c1.z;
    off4[(size_t)b * 512 + t * 2] = o0;
    off4[(size_t)b * 512 + t * 2 + 1] = o1;
}

// ---------------- place: srcw[offsets[dst]+pl] = (src,w) — no atomics --------
__global__ void place_kernel(const int* __restrict__ src, const int* __restrict__ dst,
                             const float* __restrict__ w, const int* __restrict__ offsets,
                             const ushort* __restrict__ pl, int sub,
                             int2* __restrict__ srcw, int E) {
    int e = blockIdx.x * blockDim.x + threadIdx.x;
    if (e >= E) return;
    int p = offsets[dst[e]] - sub + (int)pl[e];
    srcw[p] = make_int2(src[e], __float_as_int(w[e]));
}

// ---------------- gather: agg[n] = relu(sum_e w*sup[src] + bias) -------------
// One wave per node; lane l owns channels 2l, 2l+1 (float2). 8-edge pipeline.
__global__ void gather_nodes(const float* __restrict__ sup, const int2* __restrict__ srcw,
                             const int* __restrict__ offsets, int sub,
                             const float* __restrict__ bias,
                             float* __restrict__ out, int N) {
    int node = (blockIdx.x * blockDim.x + threadIdx.x) >> 6;
    int lane = threadIdx.x & 63;
    if (node >= N) return;
    int lo = offsets[node] - sub, hi = offsets[node + 1] - sub;
    float ax = 0.f, ay = 0.f;
    int c = lane * 2;
    int j = lo;
    for (; j + 8 <= hi; j += 8) {
        int2 s[8];
        float2 v[8];
#pragma unroll
        for (int u = 0; u < 8; ++u) s[u] = srcw[j + u];
#pragma unroll
        for (int u = 0; u < 8; ++u)
            v[u] = *(const float2*)(sup + (size_t)s[u].x * D + c);
#pragma unroll
        for (int u = 0; u < 8; ++u) {
            float wt = __int_as_float(s[u].y);
            ax = fmaf(wt, v[u].x, ax);
            ay = fmaf(wt, v[u].y, ay);
        }
    }
    for (; j < hi; ++j) {
        int2 sw = srcw[j];
        float wt = __int_as_float(sw.y);
        float2 v = *(const float2*)(sup + (size_t)sw.x * D + c);
        ax = fmaf(wt, v.x, ax); ay = fmaf(wt, v.y, ay);
    }
    float2 bi = *(const float2*)(bias + c);
    float2 o;
    o.x = fmaxf(ax + bi.x, 0.f);
    o.y = fmaxf(ay + bi.y, 0.f);
    *(float2*)(out + (size_t)node * D + c) = o;
}

// ---------------- weight transpose + bf16 convert ----------------------------
__global__ void convW(const float* __restrict__ Wx, const float* __restrict__ Wh,
                      ushort* __restrict__ wxt, ushort* __restrict__ wht) {
    int i = blockIdx.x * blockDim.x + threadIdx.x;
    if (i >= 384 * 128) return;
    int c = i >> 7, k = i & 127;
    wxt[i] = f2bf(Wx[(size_t)k * 384 + c]);
    wht[i] = f2bf(Wh[(size_t)k * 384 + c]);
}

// ---------------- fused GRU via bf16 MFMA, weights staged in LDS -------------
#define QROWS 192                 // 2 mats * 3 gates * 32 cols
#define KPAD 136
__global__ __launch_bounds__(256) void gru_mfma_lds(const float* __restrict__ h,
                                                    const float* __restrict__ hidden,
                                                    const ushort* __restrict__ wxt,
                                                    const ushort* __restrict__ wht,
                                                    const float* __restrict__ bx,
                                                    const float* __restrict__ bh,
                                                    float* __restrict__ out, int N) {
    __shared__ ushort lw[QROWS * KPAD];          // 51 KB
    int tid = threadIdx.x;
    int wid = tid >> 6, lane = tid & 63;
    int nstripes = (N + 15) >> 4;
    int stripe = blockIdx.x * 4 + wid;
    bool live = stripe < nstripes;
    int row0 = stripe * 16;
    int lr = lane & 15;
    int lk = (lane >> 4) * 8;

    short8 Ah[4], Ad[4];
    if (live) {
        const float* hrow = h + (size_t)(row0 + lr) * D + lk;
        const float* drow = hidden + (size_t)(row0 + lr) * D + lk;
#pragma unroll
        for (int ks = 0; ks < 4; ++ks) {
            float4 a0 = *(const float4*)(hrow + ks * 32);
            float4 a1 = *(const float4*)(hrow + ks * 32 + 4);
            float4 c0 = *(const float4*)(drow + ks * 32);
            float4 c1 = *(const float4*)(drow + ks * 32 + 4);
            short8 va, vc;
            va[0] = f2bf(a0.x); va[1] = f2bf(a0.y); va[2] = f2bf(a0.z); va[3] = f2bf(a0.w);
            va[4] = f2bf(a1.x); va[5] = f2bf(a1.y); va[6] = f2bf(a1.z); va[7] = f2bf(a1.w);
            vc[0] = f2bf(c0.x); vc[1] = f2bf(c0.y); vc[2] = f2bf(c0.z); vc[3] = f2bf(c0.w);
            vc[4] = f2bf(c1.x); vc[5] = f2bf(c1.y); vc[6] = f2bf(c1.z); vc[7] = f2bf(c1.w);
            Ah[ks] = va;
            Ad[ks] = vc;
        }
    }
    int orow = row0 + (lane >> 4) * 4;

    for (int q = 0; q < 4; ++q) {
        if (q) __syncthreads();
        for (int j = tid; j < QROWS * 16; j += 256) {
            int chunk = j & 15;
            int row = j >> 4;
            int mat = row >= 96;
            int r = row - (mat ? 96 : 0);
            int g = r >> 5;
            int c = r & 31;
            const ushort* srcp = (mat ? wht : wxt)
                               + ((size_t)(g * 128 + q * 32 + c) << 7) + (chunk << 3);
            *(short8*)&lw[row * KPAD + chunk * 8] = *(const short8*)srcp;
        }
        __syncthreads();
        if (!live) continue;

#pragma unroll
        for (int mt = 0; mt < 2; ++mt) {
            int cl = mt * 16 + lr;
            const ushort* bx0 = lw + (0 * 32 + cl) * KPAD + lk;
            const ushort* bx1 = lw + (1 * 32 + cl) * KPAD + lk;
            const ushort* bx2 = lw + (2 * 32 + cl) * KPAD + lk;
            const ushort* bh0 = lw + ((96 + 0 * 32) + cl) * KPAD + lk;
            const ushort* bh1 = lw + ((96 + 1 * 32) + cl) * KPAD + lk;
            const ushort* bh2 = lw + ((96 + 2 * 32) + cl) * KPAD + lk;
            f32x4 ax0{}, ax1{}, ax2{}, ah0{}, ah1{}, ah2{};
#pragma unroll
            for (int ks = 0; ks < 4; ++ks) {
                short8 w0 = *(const short8*)(bx0 + ks * 32);
                short8 w1 = *(const short8*)(bx1 + ks * 32);
                short8 w2 = *(const short8*)(bx2 + ks * 32);
                short8 v0 = *(const short8*)(bh0 + ks * 32);
                short8 v1 = *(const short8*)(bh1 + ks * 32);
                short8 v2 = *(const short8*)(bh2 + ks * 32);
                ax0 = __builtin_amdgcn_mfma_f32_16x16x32_bf16(Ah[ks], w0, ax0, 0, 0, 0);
                ax1 = __builtin_amdgcn_mfma_f32_16x16x32_bf16(Ah[ks], w1, ax1, 0, 0, 0);
                ax2 = __builtin_amdgcn_mfma_f32_16x16x32_bf16(Ah[ks], w2, ax2, 0, 0, 0);
                ah0 = __builtin_amdgcn_mfma_f32_16x16x32_bf16(Ad[ks], v0, ah0, 0, 0, 0);
                ah1 = __builtin_amdgcn_mfma_f32_16x16x32_bf16(Ad[ks], v1, ah1, 0, 0, 0);
                ah2 = __builtin_amdgcn_mfma_f32_16x16x32_bf16(Ad[ks], v2, ah2, 0, 0, 0);
            }
            int col = q * 32 + mt * 16 + lr;
            float bxr = bx[col], bxi = bx[col + 128], bxn = bx[col + 256];
            float bhr = bh[col], bhi = bh[col + 128], bhn = bh[col + 256];
#pragma unroll
            for (int r = 0; r < 4; ++r) {
                int row = orow + r;
                if (row < N) {
                    float ir = ax0[r] + bxr, hr = ah0[r] + bhr;
                    float ii = ax1[r] + bxi, hi = ah1[r] + bhi;
                    float in_ = ax2[r] + bxn, hn = ah2[r] + bhn;
                    float rg = 1.f / (1.f + __expf(-(ir + hr)));
                    float ig = 1.f / (1.f + __expf(-(ii + hi)));
                    float nx = in_ + rg * hn;
                    float ng = 1.f - 2.f / (__expf(2.f * nx) + 1.f);   // tanh(nx)
                    float hv = hidden[(size_t)row * D + col];
                    out[(size_t)row * D + col] = ng + ig * (hv - ng);
                }
            }
        }
    }
}

extern "C" void kernel_launch(void* const* d_in, const int* in_sizes, int n_in,
                              void* d_out, int out_size, void* d_ws, size_t ws_size,
                              hipStream_t stream) {
    const float* x      = (const float*)d_in[0];
    const float* hidden = (const float*)d_in[1];
    const int*   adj_src = (const int*)d_in[2];
    const int*   adj_dst = (const int*)d_in[3];
    const float* adj_w   = (const float*)d_in[4];
    const float* gcn_W   = (const float*)d_in[5];
    const float* gcn_b   = (const float*)d_in[6];
    const float* x2h_W   = (const float*)d_in[7];
    const float* x2h_b   = (const float*)d_in[8];
    const float* h2h_W   = (const float*)d_in[9];
    const float* h2h_b   = (const float*)d_in[10];
    float* out = (float*)d_out;

    const int L = 2;
    const int N = in_sizes[0] / D;        // 50000
    const int E = in_sizes[2] / L;        // 800000
    const size_t nd = (size_t)N * D;

    const int twoN   = 2 * N;
    const int NB     = (twoN + 2047) / 2048;      // scan blocks (49)
    const int padded = NB * 2048;

    char* ws = (char*)d_ws;
    float* A        = (float*)ws;                 ws += nd * 4;             // support
    float* B        = (float*)ws;                 ws += nd * 4;             // agg / h
    int*   counts2  = (int*)ws;                   ws += (size_t)padded * 4;
    int*   offsets2 = (int*)ws;                   ws += ((size_t)padded + 64) * 4;
    int*   bsum     = (int*)ws;                   ws += ((size_t)NB + 64) * 4;
    int*   bbase    = (int*)ws;                   ws += ((size_t)NB + 64) * 4;
    int2*  srcw     = (int2*)ws;                  ws += (size_t)E * 8;
    ushort* pl      = (ushort*)ws;                ws += (size_t)2 * E * 2;
    ushort* wxt     = (ushort*)ws;                ws += (size_t)384 * 128 * 2;
    ushort* wht     = (ushort*)ws;                ws += (size_t)384 * 128 * 2;

    dim3 blk(256);
    int batch_blocks = (N + ROWS_PB - 1) / ROWS_PB;
    int gat_blocks   = (N + 3) / 4;
    int edge_blocks  = (E + 255) / 256;
    int e2_blocks    = (2 * E + 255) / 256;
    int zero_blocks  = (padded / 4 + 255) / 256;
    int convw_blocks = (384 * 128 + 255) / 256;
    int nstripes     = (N + 15) / 16;
    int gru_blocks   = (nstripes + 3) / 4;

    convW<<<convw_blocks, blk, 0, stream>>>(x2h_W, h2h_W, wxt, wht);

    // CSR build: 1 atomic per edge (slot), then scan, then atomic-free place.
    zero_int4<<<zero_blocks, blk, 0, stream>>>((int4*)counts2, padded / 4);
    slot_kernel<<<e2_blocks, blk, 0, stream>>>(adj_dst, counts2, pl, 2 * E, E, N);
    scan_partial<<<NB, blk, 0, stream>>>((const int4*)counts2, bsum);
    scan_base<<<1, 64, 0, stream>>>(bsum, bbase, NB);
    scan_apply<<<NB, blk, 0, stream>>>((const int4*)counts2, bbase, (int4*)offsets2);

    const float* hcur = x;
    for (int l = 0; l < L; ++l) {
        gemm_rowbatch<<<batch_blocks, blk, 0, stream>>>(hcur, gcn_W + (size_t)l * D * D, A, N);
        place_kernel<<<edge_blocks, blk, 0, stream>>>(adj_src + (size_t)l * E,
                                                      adj_dst + (size_t)l * E,
                                                      adj_w + (size_t)l * E,
                                                      offsets2 + (size_t)l * N,
                                                      pl + (size_t)l * E, l * E,
                                                      srcw, E);
        gather_nodes<<<gat_blocks, blk, 0, stream>>>(A, srcw, offsets2 + (size_t)l * N, l * E,
                                                     gcn_b + (size_t)l * D, B, N);
        hcur = B;
    }
    gru_mfma_lds<<<gru_blocks, blk, 0, stream>>>(B, hidden, wxt, wht, x2h_b, h2h_b, out, N);
}

// Round 10
// 327.283 us; speedup vs baseline: 1.5051x; 1.1605x over previous
//
#include <hip/hip_runtime.h>

#define D 128
#define RPW 8            // rows per wave (f32 GCN gemm)
#define ROWS_PB 32       // rows per block (4 waves * 8)

typedef __attribute__((ext_vector_type(8))) short short8;
typedef __attribute__((ext_vector_type(4))) float f32x4;

static __device__ __forceinline__ ushort f2bf(float f) {
    unsigned u = __float_as_uint(f);
    unsigned r = (u + 0x7fffu + ((u >> 16) & 1u)) >> 16;   // round-to-nearest-even
    return (ushort)r;
}

// ---------------- gemm body: out_bf16 = in @ W, W staged in LDS --------------
static __device__ __forceinline__ void gemm_body(float* sw, float (*sh)[D],
                                                 const float* __restrict__ in,
                                                 const float* __restrict__ W,
                                                 ushort* __restrict__ outb,
                                                 int N, int bid, int tid) {
    int row0 = bid * ROWS_PB;
    for (int j = tid; j < D * D / 4; j += 256)
        ((float4*)sw)[j] = ((const float4*)W)[j];
    for (int i = tid; i < ROWS_PB * (D / 4); i += 256) {
        int r = i >> 5, c4 = i & 31;
        int row = row0 + r;
        float4 v = (row < N) ? ((const float4*)(in + (size_t)row * D))[c4]
                             : make_float4(0.f, 0.f, 0.f, 0.f);
        ((float4*)sh)[i] = v;
    }
    __syncthreads();
    int wid = tid >> 6, lane = tid & 63;
    int rb = wid * RPW;
    float acc0[RPW], acc1[RPW];
#pragma unroll
    for (int r = 0; r < RPW; ++r) { acc0[r] = 0.f; acc1[r] = 0.f; }
    for (int k = 0; k < D; k += 4) {
        float w0[4], w1[4];
#pragma unroll
        for (int kk = 0; kk < 4; ++kk) {
            w0[kk] = sw[(k + kk) * D + lane];
            w1[kk] = sw[(k + kk) * D + lane + 64];
        }
#pragma unroll
        for (int r = 0; r < RPW; ++r) {
            float4 a4 = *(const float4*)&sh[rb + r][k];
            acc0[r] = fmaf(a4.x, w0[0], acc0[r]); acc1[r] = fmaf(a4.x, w1[0], acc1[r]);
            acc0[r] = fmaf(a4.y, w0[1], acc0[r]); acc1[r] = fmaf(a4.y, w1[1], acc1[r]);
            acc0[r] = fmaf(a4.z, w0[2], acc0[r]); acc1[r] = fmaf(a4.z, w1[2], acc1[r]);
            acc0[r] = fmaf(a4.w, w0[3], acc0[r]); acc1[r] = fmaf(a4.w, w1[3], acc1[r]);
        }
    }
#pragma unroll
    for (int r = 0; r < RPW; ++r) {
        int row = row0 + rb + r;
        if (row < N) {
            outb[(size_t)row * D + lane] = f2bf(acc0[r]);
            outb[(size_t)row * D + lane + 64] = f2bf(acc1[r]);
        }
    }
}

// ---------------- fused: gemm(layer0) | slot histogram | convW ---------------
// Roles by blockIdx: [0,GB) gemm, [GB,GB+SB) slot, rest convW. The slot role
// is random-atomic-stall-bound (0.6% VALU) and overlaps with the VALU-bound
// gemm blocks resident on the same CUs.
__global__ __launch_bounds__(256) void fused_sgc(const float* __restrict__ x,
                                                 const float* __restrict__ W0,
                                                 ushort* __restrict__ Abf, int N,
                                                 const int* __restrict__ adj_dst,
                                                 int* __restrict__ counts,
                                                 ushort* __restrict__ pl, int E2, int E,
                                                 const float* __restrict__ Wx,
                                                 const float* __restrict__ Wh,
                                                 ushort* __restrict__ wxt,
                                                 ushort* __restrict__ wht,
                                                 int GB, int SB) {
    __shared__ float sw[D * D];          // 64 KB
    __shared__ float sh[ROWS_PB][D];     // 16 KB
    int bid = blockIdx.x, tid = threadIdx.x;
    if (bid < GB) {
        gemm_body(sw, sh, x, W0, Abf, N, bid, tid);
    } else if (bid < GB + SB) {
        int i = (bid - GB) * 256 + tid;
        if (i < E2) {
            int off = (i >= E) ? N : 0;
            pl[i] = (ushort)atomicAdd(&counts[off + adj_dst[i]], 1);
        }
    } else {
        int i = (bid - GB - SB) * 256 + tid;
        if (i < 384 * 128) {
            int c = i >> 7, k = i & 127;
            wxt[i] = f2bf(Wx[(size_t)k * 384 + c]);
            wht[i] = f2bf(Wh[(size_t)k * 384 + c]);
        }
    }
}

// ---------------- standalone gemm (layer 1) ----------------------------------
__global__ __launch_bounds__(256) void gemm_rowbatch_bf(const float* __restrict__ in,
                                                        const float* __restrict__ W,
                                                        ushort* __restrict__ outb, int N) {
    __shared__ float sw[D * D];
    __shared__ float sh[ROWS_PB][D];
    gemm_body(sw, sh, in, W, outb, N, blockIdx.x, threadIdx.x);
}

// ---------------- zero ints --------------------------------------------------
__global__ void zero_int4(int4* __restrict__ p, int n4) {
    int i = blockIdx.x * blockDim.x + threadIdx.x;
    if (i < n4) p[i] = make_int4(0, 0, 0, 0);
}

// ---------------- multi-block scan: pass 1 (block partial sums) --------------
__global__ __launch_bounds__(256) void scan_partial(const int4* __restrict__ counts4,
                                                    int* __restrict__ bsum) {
    int b = blockIdx.x, t = threadIdx.x;
    int4 c0 = counts4[(size_t)b * 512 + t * 2];
    int4 c1 = counts4[(size_t)b * 512 + t * 2 + 1];
    int s = c0.x + c0.y + c0.z + c0.w + c1.x + c1.y + c1.z + c1.w;
#pragma unroll
    for (int d = 1; d < 64; d <<= 1) s += __shfl_xor(s, d);
    __shared__ int ws[4];
    if ((t & 63) == 0) ws[t >> 6] = s;
    __syncthreads();
    if (t == 0) bsum[b] = ws[0] + ws[1] + ws[2] + ws[3];
}

// ---------------- multi-block scan: pass 2 (scan of block sums, 1 wave) ------
__global__ void scan_base(const int* __restrict__ bsum, int* __restrict__ bbase, int nb) {
    int lane = threadIdx.x;   // launched with 64 threads
    int run = 0;
    for (int c = 0; c < nb; c += 64) {
        int v = (c + lane < nb) ? bsum[c + lane] : 0;
        int inc = v;
#pragma unroll
        for (int d = 1; d < 64; d <<= 1) {
            int y = __shfl_up(inc, d);
            if (lane >= d) inc += y;
        }
        if (c + lane < nb) bbase[c + lane] = run + inc - v;
        run += __shfl(inc, 63);
    }
}

// ---------------- multi-block scan: pass 3 (apply) ---------------------------
__global__ __launch_bounds__(256) void scan_apply(const int4* __restrict__ counts4,
                                                  const int* __restrict__ bbase,
                                                  int4* __restrict__ off4) {
    __shared__ int ts[256];
    int b = blockIdx.x, t = threadIdx.x;
    int4 c0 = counts4[(size_t)b * 512 + t * 2];
    int4 c1 = counts4[(size_t)b * 512 + t * 2 + 1];
    int s = c0.x + c0.y + c0.z + c0.w + c1.x + c1.y + c1.z + c1.w;
    ts[t] = s;
    __syncthreads();
    for (int d = 1; d < 256; d <<= 1) {
        int x = ts[t];
        int y = (t >= d) ? ts[t - d] : 0;
        __syncthreads();
        ts[t] = x + y;
        __syncthreads();
    }
    int base = bbase[b] + ((t == 0) ? 0 : ts[t - 1]);
    int4 o0, o1;
    o0.x = base;
    o0.y = o0.x + c0.x;
    o0.z = o0.y + c0.y;
    o0.w = o0.z + c0.z;
    o1.x = o0.w + c0.w;
    o1.y = o1.x + c1.x;
    o1.z = o1.y + c1.y;
    o1.w = o1.z + c1.z;
    off4[(size_t)b * 512 + t * 2] = o0;
    off4[(size_t)b * 512 + t * 2 + 1] = o1;
}

// ---------------- place both layers: srcw_l[offsets[dst]+pl] = (src,w) -------
__global__ void place2_kernel(const int* __restrict__ src, const int* __restrict__ dst,
                              const float* __restrict__ w,
                              const int* __restrict__ offsets2,
                              const ushort* __restrict__ pl,
                              int2* __restrict__ srcw0, int2* __restrict__ srcw1,
                              int E, int E2, int N) {
    int i = blockIdx.x * blockDim.x + threadIdx.x;
    if (i >= E2) return;
    int l1 = i >= E;
    int node = dst[i];
    int p = offsets2[(l1 ? N : 0) + node] - (l1 ? E : 0) + (int)pl[i];
    int2 v = make_int2(src[i], __float_as_int(w[i]));
    (l1 ? srcw1 : srcw0)[p] = v;
}

// ---------------- gather (bf16 support): agg = relu(sum w*sup[src] + b) ------
// One wave per node; lane l owns channels 2l,2l+1 (one uint = 2 bf16).
__global__ void gather_nodes(const ushort* __restrict__ supb, const int2* __restrict__ srcw,
                             const int* __restrict__ offsets, int sub,
                             const float* __restrict__ bias,
                             float* __restrict__ out, int N) {
    int node = (blockIdx.x * blockDim.x + threadIdx.x) >> 6;
    int lane = threadIdx.x & 63;
    if (node >= N) return;
    int lo = offsets[node] - sub, hi = offsets[node + 1] - sub;
    float ax = 0.f, ay = 0.f;
    int c = lane * 2;
    const ushort* base = supb + c;
    int j = lo;
    for (; j + 8 <= hi; j += 8) {
        int2 s[8];
        uint v[8];
#pragma unroll
        for (int u = 0; u < 8; ++u) s[u] = srcw[j + u];
#pragma unroll
        for (int u = 0; u < 8; ++u)
            v[u] = *(const uint*)(base + ((size_t)s[u].x << 7));
#pragma unroll
        for (int u = 0; u < 8; ++u) {
            float wt = __int_as_float(s[u].y);
            ax = fmaf(wt, __uint_as_float(v[u] << 16), ax);
            ay = fmaf(wt, __uint_as_float(v[u] & 0xffff0000u), ay);
        }
    }
    for (; j < hi; ++j) {
        int2 sw = srcw[j];
        float wt = __int_as_float(sw.y);
        uint v = *(const uint*)(base + ((size_t)sw.x << 7));
        ax = fmaf(wt, __uint_as_float(v << 16), ax);
        ay = fmaf(wt, __uint_as_float(v & 0xffff0000u), ay);
    }
    float2 bi = *(const float2*)(bias + c);
    float2 o;
    o.x = fmaxf(ax + bi.x, 0.f);
    o.y = fmaxf(ay + bi.y, 0.f);
    *(float2*)(out + (size_t)node * D + c) = o;
}

// ---------------- fused GRU via bf16 MFMA, weights staged in LDS -------------
#define QROWS 192                 // 2 mats * 3 gates * 32 cols
#define KPAD 136
__global__ __launch_bounds__(256) void gru_mfma_lds(const float* __restrict__ h,
                                                    const float* __restrict__ hidden,
                                                    const ushort* __restrict__ wxt,
                                                    const ushort* __restrict__ wht,
                                                    const float* __restrict__ bx,
                                                    const float* __restrict__ bh,
                                                    float* __restrict__ out, int N) {
    __shared__ ushort lw[QROWS * KPAD];          // 51 KB
    int tid = threadIdx.x;
    int wid = tid >> 6, lane = tid & 63;
    int nstripes = (N + 15) >> 4;
    int stripe = blockIdx.x * 4 + wid;
    bool live = stripe < nstripes;
    int row0 = stripe * 16;
    int lr = lane & 15;
    int lk = (lane >> 4) * 8;

    short8 Ah[4], Ad[4];
    if (live) {
        const float* hrow = h + (size_t)(row0 + lr) * D + lk;
        const float* drow = hidden + (size_t)(row0 + lr) * D + lk;
#pragma unroll
        for (int ks = 0; ks < 4; ++ks) {
            float4 a0 = *(const float4*)(hrow + ks * 32);
            float4 a1 = *(const float4*)(hrow + ks * 32 + 4);
            float4 c0 = *(const float4*)(drow + ks * 32);
            float4 c1 = *(const float4*)(drow + ks * 32 + 4);
            short8 va, vc;
            va[0] = f2bf(a0.x); va[1] = f2bf(a0.y); va[2] = f2bf(a0.z); va[3] = f2bf(a0.w);
            va[4] = f2bf(a1.x); va[5] = f2bf(a1.y); va[6] = f2bf(a1.z); va[7] = f2bf(a1.w);
            vc[0] = f2bf(c0.x); vc[1] = f2bf(c0.y); vc[2] = f2bf(c0.z); vc[3] = f2bf(c0.w);
            vc[4] = f2bf(c1.x); vc[5] = f2bf(c1.y); vc[6] = f2bf(c1.z); vc[7] = f2bf(c1.w);
            Ah[ks] = va;
            Ad[ks] = vc;
        }
    }
    int orow = row0 + (lane >> 4) * 4;

    for (int q = 0; q < 4; ++q) {
        if (q) __syncthreads();
        for (int j = tid; j < QROWS * 16; j += 256) {
            int chunk = j & 15;
            int row = j >> 4;
            int mat = row >= 96;
            int r = row - (mat ? 96 : 0);
            int g = r >> 5;
            int c = r & 31;
            const ushort* srcp = (mat ? wht : wxt)
                               + ((size_t)(g * 128 + q * 32 + c) << 7) + (chunk << 3);
            *(short8*)&lw[row * KPAD + chunk * 8] = *(const short8*)srcp;
        }
        __syncthreads();
        if (!live) continue;

#pragma unroll
        for (int mt = 0; mt < 2; ++mt) {
            int cl = mt * 16 + lr;
            const ushort* bx0 = lw + (0 * 32 + cl) * KPAD + lk;
            const ushort* bx1 = lw + (1 * 32 + cl) * KPAD + lk;
            const ushort* bx2 = lw + (2 * 32 + cl) * KPAD + lk;
            const ushort* bh0 = lw + ((96 + 0 * 32) + cl) * KPAD + lk;
            const ushort* bh1 = lw + ((96 + 1 * 32) + cl) * KPAD + lk;
            const ushort* bh2 = lw + ((96 + 2 * 32) + cl) * KPAD + lk;
            f32x4 ax0{}, ax1{}, ax2{}, ah0{}, ah1{}, ah2{};
#pragma unroll
            for (int ks = 0; ks < 4; ++ks) {
                short8 w0 = *(const short8*)(bx0 + ks * 32);
                short8 w1 = *(const short8*)(bx1 + ks * 32);
                short8 w2 = *(const short8*)(bx2 + ks * 32);
                short8 v0 = *(const short8*)(bh0 + ks * 32);
                short8 v1 = *(const short8*)(bh1 + ks * 32);
                short8 v2 = *(const short8*)(bh2 + ks * 32);
                ax0 = __builtin_amdgcn_mfma_f32_16x16x32_bf16(Ah[ks], w0, ax0, 0, 0, 0);
                ax1 = __builtin_amdgcn_mfma_f32_16x16x32_bf16(Ah[ks], w1, ax1, 0, 0, 0);
                ax2 = __builtin_amdgcn_mfma_f32_16x16x32_bf16(Ah[ks], w2, ax2, 0, 0, 0);
                ah0 = __builtin_amdgcn_mfma_f32_16x16x32_bf16(Ad[ks], v0, ah0, 0, 0, 0);
                ah1 = __builtin_amdgcn_mfma_f32_16x16x32_bf16(Ad[ks], v1, ah1, 0, 0, 0);
                ah2 = __builtin_amdgcn_mfma_f32_16x16x32_bf16(Ad[ks], v2, ah2, 0, 0, 0);
            }
            int col = q * 32 + mt * 16 + lr;
            float bxr = bx[col], bxi = bx[col + 128], bxn = bx[col + 256];
            float bhr = bh[col], bhi = bh[col + 128], bhn = bh[col + 256];
#pragma unroll
            for (int r = 0; r < 4; ++r) {
                int row = orow + r;
                if (row < N) {
                    float ir = ax0[r] + bxr, hr = ah0[r] + bhr;
                    float ii = ax1[r] + bxi, hi = ah1[r] + bhi;
                    float in_ = ax2[r] + bxn, hn = ah2[r] + bhn;
                    float rg = 1.f / (1.f + __expf(-(ir + hr)));
                    float ig = 1.f / (1.f + __expf(-(ii + hi)));
                    float nx = in_ + rg * hn;
                    float ng = 1.f - 2.f / (__expf(2.f * nx) + 1.f);   // tanh(nx)
                    float hv = hidden[(size_t)row * D + col];
                    out[(size_t)row * D + col] = ng + ig * (hv - ng);
                }
            }
        }
    }
}

extern "C" void kernel_launch(void* const* d_in, const int* in_sizes, int n_in,
                              void* d_out, int out_size, void* d_ws, size_t ws_size,
                              hipStream_t stream) {
    const float* x      = (const float*)d_in[0];
    const float* hidden = (const float*)d_in[1];
    const int*   adj_src = (const int*)d_in[2];
    const int*   adj_dst = (const int*)d_in[3];
    const float* adj_w   = (const float*)d_in[4];
    const float* gcn_W   = (const float*)d_in[5];
    const float* gcn_b   = (const float*)d_in[6];
    const float* x2h_W   = (const float*)d_in[7];
    const float* x2h_b   = (const float*)d_in[8];
    const float* h2h_W   = (const float*)d_in[9];
    const float* h2h_b   = (const float*)d_in[10];
    float* out = (float*)d_out;

    const int L = 2;
    const int N = in_sizes[0] / D;        // 50000
    const int E = in_sizes[2] / L;        // 800000
    const size_t nd = (size_t)N * D;

    const int twoN   = 2 * N;
    const int NB     = (twoN + 2047) / 2048;      // scan blocks (49)
    const int padded = NB * 2048;

    char* ws = (char*)d_ws;
    ushort* Abf     = (ushort*)ws;                ws += nd * 2;             // bf16 support
    float*  B       = (float*)ws;                 ws += nd * 4;             // agg / h (f32)
    int*   counts2  = (int*)ws;                   ws += (size_t)padded * 4;
    int*   offsets2 = (int*)ws;                   ws += ((size_t)padded + 64) * 4;
    int*   bsum     = (int*)ws;                   ws += ((size_t)NB + 64) * 4;
    int*   bbase    = (int*)ws;                   ws += ((size_t)NB + 64) * 4;
    int2*  srcw0    = (int2*)ws;                  ws += (size_t)E * 8;
    int2*  srcw1    = (int2*)ws;                  ws += (size_t)E * 8;
    ushort* pl      = (ushort*)ws;                ws += (size_t)2 * E * 2;
    ushort* wxt     = (ushort*)ws;                ws += (size_t)384 * 128 * 2;
    ushort* wht     = (ushort*)ws;                ws += (size_t)384 * 128 * 2;

    dim3 blk(256);
    int batch_blocks = (N + ROWS_PB - 1) / ROWS_PB;       // 1563
    int gat_blocks   = (N + 3) / 4;
    int e2_blocks    = (2 * E + 255) / 256;               // 6250
    int zero_blocks  = (padded / 4 + 255) / 256;
    int convw_blocks = (384 * 128 + 255) / 256;           // 192
    int nstripes     = (N + 15) / 16;
    int gru_blocks   = (nstripes + 3) / 4;

    // 1) zero counters
    zero_int4<<<zero_blocks, blk, 0, stream>>>((int4*)counts2, padded / 4);
    // 2) fused: gemm layer0 | slot histogram (1 atomic/edge) | convW
    fused_sgc<<<batch_blocks + e2_blocks + convw_blocks, blk, 0, stream>>>(
        x, gcn_W, Abf, N, adj_dst, counts2, pl, 2 * E, E,
        x2h_W, h2h_W, wxt, wht, batch_blocks, e2_blocks);
    // 3) scan
    scan_partial<<<NB, blk, 0, stream>>>((const int4*)counts2, bsum);
    scan_base<<<1, 64, 0, stream>>>(bsum, bbase, NB);
    scan_apply<<<NB, blk, 0, stream>>>((const int4*)counts2, bbase, (int4*)offsets2);
    // 4) place both layers (atomic-free)
    place2_kernel<<<e2_blocks, blk, 0, stream>>>(adj_src, adj_dst, adj_w, offsets2, pl,
                                                 srcw0, srcw1, E, 2 * E, N);
    // 5) layer 0 gather, layer 1 gemm+gather
    gather_nodes<<<gat_blocks, blk, 0, stream>>>(Abf, srcw0, offsets2, 0,
                                                 gcn_b, B, N);
    gemm_rowbatch_bf<<<batch_blocks, blk, 0, stream>>>(B, gcn_W + (size_t)D * D, Abf, N);
    gather_nodes<<<gat_blocks, blk, 0, stream>>>(Abf, srcw1, offsets2 + N, E,
                                                 gcn_b + D, B, N);
    // 6) GRU
    gru_mfma_lds<<<gru_blocks, blk, 0, stream>>>(B, hidden, wxt, wht, x2h_b, h2h_b, out, N);
}